// Round 1
// baseline (316.773 us; speedup 1.0000x reference)
//
#include <hip/hip_runtime.h>

#pragma clang fp contract(off)

#define NBOX 262144
#define NCLS 80
#define ROWS 85
#define CAP 1024
#define POOL 8192

typedef unsigned long long ull;

// ---------------- init: zero per-class counters + pool counter
__global__ __launch_bounds__(128) void k_init(int* __restrict__ ccount,
                                              int* __restrict__ pool_count) {
    const int t = threadIdx.x;
    if (t < NCLS) ccount[t] = 0;
    if (t == NCLS) *pool_count = 0;
}

// ---------------- stage1: obj-scan + class argmax + DIRECT per-class bucket scatter
__global__ __launch_bounds__(256) void k_stage1(const float* __restrict__ det,
                                                int* __restrict__ ccount,
                                                ull* __restrict__ key2,
                                                float* __restrict__ conf2,
                                                float4* __restrict__ box2) {
    __shared__ int s_wl[256];
    __shared__ float s_obj[256];
    __shared__ int wsum[4];
    __shared__ int s_nv;
    const int t = threadIdx.x, lane = t & 63, wave = t >> 6;
    const int bi = blockIdx.x * 256 + t;

    // phase 1: one obj per thread (line-granular fetch, ~19% of input bytes)
    float obj = det[(size_t)bi * ROWS + 4];
    bool valid = (obj >= 0.8f);   // CONF_THRES
    ull m = __ballot(valid);
    if (lane == 0) wsum[wave] = (int)__popcll(m);
    __syncthreads();
    if (t == 0) {
        int s = 0;
        #pragma unroll
        for (int w = 0; w < 4; w++) { int cc = wsum[w]; wsum[w] = s; s += cc; }
        s_nv = s;
    }
    __syncthreads();
    if (valid) {
        int r = wsum[wave] + (int)__popcll(m & ((1ull << lane) - 1ull));
        s_wl[r] = t;
        s_obj[r] = obj;
    }
    __syncthreads();
    const int nv = s_nv;

    // phase 2: 16 lanes per valid box; j = k*16 + c covers classes 0..79 exactly
    const int grp = t >> 4, c = t & 15;
    for (int r0 = 0; r0 < nv; r0 += 16) {
        int widx = r0 + grp;
        if (widx < nv) {
            int b = s_wl[widx];
            const float* p = det + (size_t)(blockIdx.x * 256 + b) * ROWS;
            float aux = (c < 5) ? p[c] : 0.0f;    // x y w h obj
            float v0 = p[5 + c];
            float v1 = p[21 + c];
            float v2 = p[37 + c];
            float v3 = p[53 + c];
            float v4 = p[69 + c];
            float mv = v0; int mj = c;
            if (v1 > mv) { mv = v1; mj = 16 + c; }   // ascending j, strict >
            if (v2 > mv) { mv = v2; mj = 32 + c; }
            if (v3 > mv) { mv = v3; mj = 48 + c; }
            if (v4 > mv) { mv = v4; mj = 64 + c; }
            #pragma unroll
            for (int off = 8; off; off >>= 1) {      // group argmax, ties smaller j
                float ov = __shfl_xor(mv, off);
                int oj = __shfl_xor(mj, off);
                if (ov > mv || (ov == mv && oj < mj)) { mv = ov; mj = oj; }
            }
            int gb = lane & 48;                      // group base within wave
            float x = __shfl(aux, gb + 0);
            float y = __shfl(aux, gb + 1);
            float w = __shfl(aux, gb + 2);
            float h = __shfl(aux, gb + 3);
            if (c == 0) {
                float ob = s_obj[widx];
                float score = ob * mv;
                float hw = w * 0.5f, hh = h * 0.5f;
                int gi = blockIdx.x * 256 + b;
                // direct class-bucket scatter; within-class order is irrelevant
                // (keys unique; pick loop always takes the global min key)
                int r = atomicAdd(&ccount[mj], 1);
                if (r < CAP) {
                    int pos = (mj << 10) + r;
                    key2[pos] = ((ull)(~__float_as_uint(score)) << 32) | (unsigned)gi;
                    conf2[pos] = mv;
                    box2[pos] = make_float4(x - hw, y - hh, x + hw, y + hh);
                }
            }
        }
    }
}

// ---------------- exact alive count (wave-uniform)
template <int L>
__device__ __forceinline__ int exact_alive(ull (&k)[L]) {
    int a = 0;
    #pragma unroll
    for (int j = 0; j < L; j++) a += (int)__popcll(__ballot(k[j] != ~0ULL));
    return a;
}

// ---------------- greedy pick loop; alive refreshed every 8 picks only
// np<300 early exit: a class's 301st pick can't reach the global top-300
// (picks emerge in descending score order per class).
template <int L>
__device__ __forceinline__ void pick_loop(ull (&k)[L], float4 (&bx)[L], float (&cf)[L],
                                          int lane, int& alive, int& np,
                                          ull* pkey, float* pconf, int stopAt) {
    while (alive > stopAt && np < 300) {
        ull lm = k[0]; int lj = 0;
        #pragma unroll
        for (int j = 1; j < L; j++) if (k[j] < lm) { lm = k[j]; lj = j; }
        ull gm = lm;
        #pragma unroll
        for (int off = 32; off; off >>= 1) { ull o = __shfl_xor(gm, off); if (o < gm) gm = o; }
        if (gm == ~0ULL) { alive = 0; break; }
        float4 cb = bx[0]; float cc = cf[0];
        #pragma unroll
        for (int j = 1; j < L; j++) if (j == lj) { cb = bx[j]; cc = cf[j]; }
        ull wb = __ballot(lm == gm);              // unique winner (keys unique)
        int wl2 = (int)__ffsll((long long)wb) - 1;
        cb.x = __shfl(cb.x, wl2); cb.y = __shfl(cb.y, wl2);
        cb.z = __shfl(cb.z, wl2); cb.w = __shfl(cb.w, wl2);
        cc = __shfl(cc, wl2);
        if (lane == 0) { pkey[np] = gm; pconf[np] = cc; }
        np++;
        float a1 = (cb.z - cb.x + 1.0f) * (cb.w - cb.y + 1.0f);
        #pragma unroll
        for (int j = 0; j < L; j++) {
            if (k[j] != ~0ULL) {                  // winner self-kills via IoU=1
                float4 b = bx[j];
                float xx1 = fmaxf(cb.x, b.x), yy1 = fmaxf(cb.y, b.y);
                float xx2 = fminf(cb.z, b.z), yy2 = fminf(cb.w, b.w);
                float iw = xx2 - xx1 + 1.0f, ih = yy2 - yy1 + 1.0f;
                float inter = fmaxf(iw, 0.0f) * fmaxf(ih, 0.0f);
                float a2 = (b.z - b.x + 1.0f) * (b.w - b.y + 1.0f);
                float iou = inter / (a1 + a2 - inter + 1e-16f);
                if (iou > 0.4f) k[j] = ~0ULL;     // NMS_THRES
            }
        }
        if ((np & 7) == 0) alive = exact_alive(k);   // stale-high is safe
    }
}

// ---------------- register compaction LF -> LT via LDS (single wave; alive EXACT)
template <int LF, int LT>
__device__ __forceinline__ void compact_regs(ull (&k)[LF], float4 (&bx)[LF], float (&cf)[LF],
                                             ull (&k2)[LT], float4 (&b2)[LT], float (&c2)[LT],
                                             int lane, int alive,
                                             ull* dk, float4* db, float* dc) {
    int ci = 0;
    #pragma unroll
    for (int j = 0; j < LF; j++) if (k[j] != ~0ULL) ci++;
    int inc = ci;
    for (int off = 1; off < 64; off <<= 1) {
        int o = __shfl_up(inc, off);
        if (lane >= off) inc += o;
    }
    int wp = inc - ci;
    #pragma unroll
    for (int j = 0; j < LF; j++)
        if (k[j] != ~0ULL) { dk[wp] = k[j]; db[wp] = bx[j]; dc[wp] = cf[j]; wp++; }
    #pragma unroll
    for (int j = 0; j < LT; j++) {
        int pos = lane + (j << 6);
        bool ok = pos < alive;
        k2[j] = ok ? dk[pos] : ~0ULL;
        b2[j] = ok ? db[pos] : make_float4(0.f, 0.f, 0.f, 0.f);
        c2[j] = ok ? dc[pos] : 0.0f;
    }
}

// ---------------- stage2+3: single-wave register greedy NMS on class bucket
__global__ __launch_bounds__(64) void k_nms(const int* __restrict__ ccount,
                                            const ull* __restrict__ key2,
                                            const float* __restrict__ conf2,
                                            const float4* __restrict__ box2,
                                            ull* __restrict__ pool_key,
                                            float* __restrict__ pool_conf,
                                            int* __restrict__ pool_cls,
                                            int* __restrict__ pool_count) {
    __shared__ ull sk[CAP];      // compact_regs scratch
    __shared__ float4 sb[CAP];
    __shared__ float sc[CAP];
    __shared__ ull pkey[CAP];
    __shared__ float pconf[CAP];
    const int c = blockIdx.x, lane = threadIdx.x;
    const int n = min(ccount[c], CAP);
    const int s0 = c << 10;

    ull k16[16]; float4 b16[16]; float c16[16];
    #pragma unroll
    for (int j = 0; j < 16; j++) {
        int pos = lane + (j << 6);
        bool ok = pos < n;
        k16[j] = ok ? key2[s0 + pos] : ~0ULL;     // coalesced segment loads
        b16[j] = ok ? box2[s0 + pos] : make_float4(0.f, 0.f, 0.f, 0.f);
        c16[j] = ok ? conf2[s0 + pos] : 0.0f;
    }
    int alive = n, np = 0;
    pick_loop<16>(k16, b16, c16, lane, alive, np, pkey, pconf, 256);
    alive = exact_alive(k16);
    ull k4[4]; float4 b4[4]; float c4[4];
    compact_regs<16, 4>(k16, b16, c16, k4, b4, c4, lane, alive, sk, sb, sc);
    pick_loop<4>(k4, b4, c4, lane, alive, np, pkey, pconf, 64);
    alive = exact_alive(k4);
    ull k1[1]; float4 b1[1]; float c1[1];
    compact_regs<4, 1>(k4, b4, c4, k1, b1, c1, lane, alive, sk, sb, sc);
    pick_loop<1>(k1, b1, c1, lane, alive, np, pkey, pconf, 0);

    int npw = min(np, 300);
    int base = 0;
    if (lane == 0 && npw) base = atomicAdd(pool_count, npw);
    base = __shfl(base, 0);
    for (int j = lane; j < npw; j += 64) {
        int pp = base + j;
        if (pp < POOL) {
            ull gm = pkey[j];
            // repack: bit63=0 | 31 score bits | 18 orig_idx | 14 pool_idx
            pool_key[pp] = ((ull)((unsigned)(gm >> 32) & 0x7FFFFFFFu) << 32)
                         | ((gm & 0xFFFFFFFFull) << 14) | (ull)pp;
            pool_conf[pp] = pconf[j];
            pool_cls[pp] = c;
        }
    }
}

// ---------------- single-wave in-register bitonic sort of 512 (8/lane, i = r*64+lane)
__device__ __forceinline__ void bsort512(ull (&x)[8], int lane) {
    #pragma unroll
    for (int k = 2; k <= 512; k <<= 1) {
        #pragma unroll
        for (int j = k >> 1; j >= 64; j >>= 1) {
            const int jr = j >> 6;
            #pragma unroll
            for (int r2 = 0; r2 < 8; r2++) {
                if ((r2 & jr) == 0) {
                    const bool asc = (((r2 << 6) & k) == 0);
                    ull a = x[r2], b = x[r2 | jr];
                    if ((a > b) == asc) { x[r2] = b; x[r2 | jr] = a; }
                }
            }
        }
        #pragma unroll
        for (int j = ((k >> 1) > 32 ? 32 : (k >> 1)); j >= 1; j >>= 1) {
            #pragma unroll
            for (int r2 = 0; r2 < 8; r2++) {
                int i = (r2 << 6) + lane;
                bool asc = ((i & k) == 0);
                ull o = __shfl_xor(x[r2], j);
                bool lower = ((lane & j) == 0);
                ull mn = x[r2] < o ? x[r2] : o;
                ull mx2 = x[r2] < o ? o : x[r2];
                x[r2] = (asc == lower) ? mn : mx2;
            }
        }
    }
}

// ---------------- stage4: prefix-skipped radix-select + single-wave 2-pass sort
__global__ __launch_bounds__(256) void k_final(const ull* __restrict__ pool_key,
                                               const float* __restrict__ pool_conf,
                                               const int* __restrict__ pool_cls,
                                               const int* __restrict__ pool_count,
                                               float* __restrict__ out) {
    __shared__ int s_red[4];
    __shared__ int s_stat[2];
    __shared__ ull s_mm[8];
    __shared__ ull s_buf[512];
    __shared__ unsigned s_cb[512];
    __shared__ unsigned s_cl[512];
    const int t = threadIdx.x, wave = t >> 6, lane = t & 63;
    const int K = min(*pool_count, POOL);
    ull key[32];
    #pragma unroll
    for (int j = 0; j < 32; j++) {
        int pos = t + (j << 8);
        key[j] = (pos < K) ? pool_key[pos] : ~0ULL;
    }

    const bool selAll = (K <= 511);
    int bsh = 63; ull p = 0;
    if (!selAll) {
        ull mn = ~0ULL, mx = 0;
        #pragma unroll
        for (int j = 0; j < 32; j++) {
            ull kk = key[j];
            if (kk != ~0ULL) { if (kk < mn) mn = kk; if (kk > mx) mx = kk; }
        }
        #pragma unroll
        for (int off = 32; off; off >>= 1) {
            ull on = __shfl_xor(mn, off), ox = __shfl_xor(mx, off);
            if (on < mn) mn = on;
            if (ox > mx) mx = ox;
        }
        if (lane == 0) { s_mm[wave * 2] = mn; s_mm[wave * 2 + 1] = mx; }
        __syncthreads();
        mn = min(min(s_mm[0], s_mm[2]), min(s_mm[4], s_mm[6]));
        mx = max(max(s_mm[1], s_mm[3]), max(s_mm[5], s_mm[7]));
        ull diff = mn ^ mx;
        int hb = 63 - __builtin_clzll(diff);
        int r = 300, cand = K, b = hb;
        p = mn >> (hb + 1);
        while (b >= 13 && cand > 212) {
            int c0 = 0;
            #pragma unroll
            for (int j = 0; j < 32; j++) {
                ull kk = key[j];
                if ((kk >> (b + 1)) == p && (((kk >> b) & 1ull) == 0)) c0++;
            }
            #pragma unroll
            for (int off = 32; off; off >>= 1) c0 += __shfl_xor(c0, off);
            if (lane == 0) s_red[wave] = c0;
            __syncthreads();
            if (t == 0) s_stat[0] = s_red[0] + s_red[1] + s_red[2] + s_red[3];
            __syncthreads();
            int cnt0 = s_stat[0];
            if (r <= cnt0) { cand = cnt0; p = p << 1; }
            else { r -= cnt0; cand -= cnt0; p = (p << 1) | 1ull; }
            b--;
        }
        bsh = b + 1;
    }

    if (t == 0) s_stat[1] = 0;
    __syncthreads();
    int ci = 0;
    #pragma unroll
    for (int j = 0; j < 32; j++) {
        ull kk = key[j];
        bool sel = selAll ? ((kk >> 63) == 0) : ((kk >> bsh) <= p);
        if (sel) ci++;
    }
    int inc = ci;
    for (int off = 1; off < 64; off <<= 1) {
        int o = __shfl_up(inc, off);
        if (lane >= off) inc += o;
    }
    int wtot = __shfl(inc, 63);
    int wbase2 = 0;
    if (lane == 0 && wtot) wbase2 = atomicAdd(&s_stat[1], wtot);
    wbase2 = __shfl(wbase2, 0);
    int wp = wbase2 + inc - ci;
    #pragma unroll
    for (int j = 0; j < 32; j++) {
        ull kk = key[j];
        bool sel = selAll ? ((kk >> 63) == 0) : ((kk >> bsh) <= p);
        if (sel) s_buf[wp++] = kk;
    }
    __syncthreads();
    const int S = s_stat[1];
    for (int i = t; i < 512; i += 256) if (i >= S) s_buf[i] = ~0ULL;
    __syncthreads();
    if (wave != 0) return;

    #pragma clang loop unroll(disable)
    for (int pass = 0; pass < 2; pass++) {
        ull x[8];
        #pragma unroll
        for (int r2 = 0; r2 < 8; r2++) x[r2] = s_buf[(r2 << 6) + lane];
        bsort512(x, lane);
        if (pass == 0) {
            #pragma unroll
            for (int r2 = 0; r2 < 8; r2++) {
                int i = (r2 << 6) + lane;
                ull kk = x[r2];
                ull k2 = ~0ULL;
                if (i < 300 && kk != ~0ULL) {
                    int pidx = (int)(kk & 0x3FFFull);
                    unsigned cb = __float_as_uint(pool_conf[pidx]);
                    unsigned cl = (unsigned)pool_cls[pidx];
                    s_cb[i] = cb; s_cl[i] = cl;
                    k2 = ((ull)(~cb) << 32) | (unsigned)(~i);   // conf desc, rank desc
                }
                s_buf[i] = k2;
            }
        } else {
            #pragma unroll
            for (int r2 = 0; r2 < 8; r2++) {
                int i = (r2 << 6) + lane;
                if (i < 300) {
                    ull kk = x[r2];
                    float idv = 0.0f, pv = 0.0f;
                    if (kk != ~0ULL) {
                        int slot = (int)(~(unsigned)(kk & 0xFFFFFFFFull));
                        pv = __uint_as_float(s_cb[slot]);
                        idv = (float)(int)s_cl[slot];
                    }
                    out[i] = idv;        // ids (1,300)
                    out[300 + i] = pv;   // probs (300,)
                }
            }
        }
    }
}

extern "C" void kernel_launch(void* const* d_in, const int* in_sizes, int n_in,
                              void* d_out, int out_size, void* d_ws, size_t ws_size,
                              hipStream_t stream) {
    const float* det = (const float*)d_in[0];
    float* out = (float*)d_out;
    char* ws = (char*)d_ws;

    int* ccount = (int*)(ws + 0);                 // 80*4 = 320
    int* pool_count = (int*)(ws + 320);           // 4
    ull* key2 = (ull*)(ws + 384);                 // 80*1024*8 = 655360
    float* conf2 = (float*)(ws + 655744);         // 80*1024*4 = 327680
    float4* box2 = (float4*)(ws + 983424);        // 80*1024*16 = 1310720 (16B aligned)
    ull* pool_key = (ull*)(ws + 2294144);         // POOL*8 = 65536
    float* pool_conf = (float*)(ws + 2359680);    // POOL*4 = 32768
    int* pool_cls = (int*)(ws + 2392448);         // POOL*4 = 32768

    k_init<<<1, 128, 0, stream>>>(ccount, pool_count);
    k_stage1<<<NBOX / 256, 256, 0, stream>>>(det, ccount, key2, conf2, box2);
    k_nms<<<NCLS, 64, 0, stream>>>(ccount, key2, conf2, box2,
                                   pool_key, pool_conf, pool_cls, pool_count);
    k_final<<<1, 256, 0, stream>>>(pool_key, pool_conf, pool_cls, pool_count, out);
}

// Round 2
// 178.936 us; speedup vs baseline: 1.7703x; 1.7703x over previous
//
#include <hip/hip_runtime.h>

#pragma clang fp contract(off)

#define NBOX 262144
#define NCLS 80
#define ROWS 85
#define CAP 1024
#define NSUB 8          // sub-buckets per class (contention spreading)
#define SUBCAP 128      // CAP / NSUB; mean load ~82, 5.1 sigma headroom
#define POOL 8192

typedef unsigned long long ull;

// ---------------- init: zero padded per-(class,sub) counters + pool counter
// counters are padded to one per 64B cacheline: index ((c*NSUB+s)<<4)
__global__ __launch_bounds__(1024) void k_init(int* __restrict__ cnt_pad,
                                               int* __restrict__ pool_count) {
    const int t = threadIdx.x;
    for (int i = t; i < NCLS * NSUB * 16; i += 1024) cnt_pad[i] = 0;
    if (t == 0) *pool_count = 0;
}

// ---------------- stage1: obj-scan + class argmax + per-class sub-bucket scatter
__global__ __launch_bounds__(256) void k_stage1(const float* __restrict__ det,
                                                int* __restrict__ cnt_pad,
                                                ull* __restrict__ key2,
                                                float* __restrict__ conf2,
                                                float4* __restrict__ box2) {
    __shared__ int s_wl[256];
    __shared__ float s_obj[256];
    __shared__ int wsum[4];
    __shared__ int s_nv;
    const int t = threadIdx.x, lane = t & 63, wave = t >> 6;
    const int bi = blockIdx.x * 256 + t;
    const int sb = blockIdx.x & (NSUB - 1);   // this block's sub-bucket

    // phase 1: one obj per thread (line-granular fetch, ~19% of input bytes)
    float obj = det[(size_t)bi * ROWS + 4];
    bool valid = (obj >= 0.8f);   // CONF_THRES
    ull m = __ballot(valid);
    if (lane == 0) wsum[wave] = (int)__popcll(m);
    __syncthreads();
    if (t == 0) {
        int s = 0;
        #pragma unroll
        for (int w = 0; w < 4; w++) { int cc = wsum[w]; wsum[w] = s; s += cc; }
        s_nv = s;
    }
    __syncthreads();
    if (valid) {
        int r = wsum[wave] + (int)__popcll(m & ((1ull << lane) - 1ull));
        s_wl[r] = t;
        s_obj[r] = obj;
    }
    __syncthreads();
    const int nv = s_nv;

    // phase 2: 16 lanes per valid box; j = k*16 + c covers classes 0..79 exactly
    const int grp = t >> 4, c = t & 15;
    for (int r0 = 0; r0 < nv; r0 += 16) {
        int widx = r0 + grp;
        if (widx < nv) {
            int b = s_wl[widx];
            const float* p = det + (size_t)(blockIdx.x * 256 + b) * ROWS;
            float aux = (c < 5) ? p[c] : 0.0f;    // x y w h obj
            float v0 = p[5 + c];
            float v1 = p[21 + c];
            float v2 = p[37 + c];
            float v3 = p[53 + c];
            float v4 = p[69 + c];
            float mv = v0; int mj = c;
            if (v1 > mv) { mv = v1; mj = 16 + c; }   // ascending j, strict >
            if (v2 > mv) { mv = v2; mj = 32 + c; }
            if (v3 > mv) { mv = v3; mj = 48 + c; }
            if (v4 > mv) { mv = v4; mj = 64 + c; }
            #pragma unroll
            for (int off = 8; off; off >>= 1) {      // group argmax, ties smaller j
                float ov = __shfl_xor(mv, off);
                int oj = __shfl_xor(mj, off);
                if (ov > mv || (ov == mv && oj < mj)) { mv = ov; mj = oj; }
            }
            int gb = lane & 48;                      // group base within wave
            float x = __shfl(aux, gb + 0);
            float y = __shfl(aux, gb + 1);
            float w = __shfl(aux, gb + 2);
            float h = __shfl(aux, gb + 3);
            if (c == 0) {
                float ob = s_obj[widx];
                float score = ob * mv;
                float hw = w * 0.5f, hh = h * 0.5f;
                int gi = blockIdx.x * 256 + b;
                // sub-bucket reservation: 640 cacheline-padded counters,
                // ~82 atomics per counter -> no serialization hot spot
                int r = atomicAdd(&cnt_pad[((mj * NSUB + sb) << 4)], 1);
                if (r < SUBCAP) {
                    int pos = (mj << 10) + (sb << 7) + r;
                    key2[pos] = ((ull)(~__float_as_uint(score)) << 32) | (unsigned)gi;
                    conf2[pos] = mv;
                    box2[pos] = make_float4(x - hw, y - hh, x + hw, y + hh);
                }
            }
        }
    }
}

// ---------------- exact alive count (wave-uniform)
template <int L>
__device__ __forceinline__ int exact_alive(ull (&k)[L]) {
    int a = 0;
    #pragma unroll
    for (int j = 0; j < L; j++) a += (int)__popcll(__ballot(k[j] != ~0ULL));
    return a;
}

// ---------------- greedy pick loop; alive refreshed every 8 picks only
// np<300 early exit: a class's 301st pick can't reach the global top-300
template <int L>
__device__ __forceinline__ void pick_loop(ull (&k)[L], float4 (&bx)[L], float (&cf)[L],
                                          int lane, int& alive, int& np,
                                          ull* pkey, float* pconf, int stopAt) {
    while (alive > stopAt && np < 300) {
        ull lm = k[0]; int lj = 0;
        #pragma unroll
        for (int j = 1; j < L; j++) if (k[j] < lm) { lm = k[j]; lj = j; }
        ull gm = lm;
        #pragma unroll
        for (int off = 32; off; off >>= 1) { ull o = __shfl_xor(gm, off); if (o < gm) gm = o; }
        if (gm == ~0ULL) { alive = 0; break; }
        float4 cb = bx[0]; float cc = cf[0];
        #pragma unroll
        for (int j = 1; j < L; j++) if (j == lj) { cb = bx[j]; cc = cf[j]; }
        ull wb = __ballot(lm == gm);              // unique winner (keys unique)
        int wl2 = (int)__ffsll((long long)wb) - 1;
        cb.x = __shfl(cb.x, wl2); cb.y = __shfl(cb.y, wl2);
        cb.z = __shfl(cb.z, wl2); cb.w = __shfl(cb.w, wl2);
        cc = __shfl(cc, wl2);
        if (lane == 0) { pkey[np] = gm; pconf[np] = cc; }
        np++;
        float a1 = (cb.z - cb.x + 1.0f) * (cb.w - cb.y + 1.0f);
        #pragma unroll
        for (int j = 0; j < L; j++) {
            if (k[j] != ~0ULL) {                  // winner self-kills via IoU=1
                float4 b = bx[j];
                float xx1 = fmaxf(cb.x, b.x), yy1 = fmaxf(cb.y, b.y);
                float xx2 = fminf(cb.z, b.z), yy2 = fminf(cb.w, b.w);
                float iw = xx2 - xx1 + 1.0f, ih = yy2 - yy1 + 1.0f;
                float inter = fmaxf(iw, 0.0f) * fmaxf(ih, 0.0f);
                float a2 = (b.z - b.x + 1.0f) * (b.w - b.y + 1.0f);
                float iou = inter / (a1 + a2 - inter + 1e-16f);
                if (iou > 0.4f) k[j] = ~0ULL;     // NMS_THRES
            }
        }
        if ((np & 7) == 0) alive = exact_alive(k);   // stale-high is safe
    }
}

// ---------------- register compaction LF -> LT via LDS (single wave; alive EXACT)
template <int LF, int LT>
__device__ __forceinline__ void compact_regs(ull (&k)[LF], float4 (&bx)[LF], float (&cf)[LF],
                                             ull (&k2)[LT], float4 (&b2)[LT], float (&c2)[LT],
                                             int lane, int alive,
                                             ull* dk, float4* db, float* dc) {
    int ci = 0;
    #pragma unroll
    for (int j = 0; j < LF; j++) if (k[j] != ~0ULL) ci++;
    int inc = ci;
    for (int off = 1; off < 64; off <<= 1) {
        int o = __shfl_up(inc, off);
        if (lane >= off) inc += o;
    }
    int wp = inc - ci;
    #pragma unroll
    for (int j = 0; j < LF; j++)
        if (k[j] != ~0ULL) { dk[wp] = k[j]; db[wp] = bx[j]; dc[wp] = cf[j]; wp++; }
    #pragma unroll
    for (int j = 0; j < LT; j++) {
        int pos = lane + (j << 6);
        bool ok = pos < alive;
        k2[j] = ok ? dk[pos] : ~0ULL;
        b2[j] = ok ? db[pos] : make_float4(0.f, 0.f, 0.f, 0.f);
        c2[j] = ok ? dc[pos] : 0.0f;
    }
}

// ---------------- stage2+3: single-wave register greedy NMS on class bucket
__global__ __launch_bounds__(64) void k_nms(const int* __restrict__ cnt_pad,
                                            const ull* __restrict__ key2,
                                            const float* __restrict__ conf2,
                                            const float4* __restrict__ box2,
                                            ull* __restrict__ pool_key,
                                            float* __restrict__ pool_conf,
                                            int* __restrict__ pool_cls,
                                            int* __restrict__ pool_count) {
    __shared__ ull sk[CAP];      // compact_regs scratch
    __shared__ float4 sb[CAP];
    __shared__ float sc[CAP];
    __shared__ ull pkey[CAP];
    __shared__ float pconf[CAP];
    const int c = blockIdx.x, lane = threadIdx.x;
    const int s0 = c << 10;

    // per-sub-bucket valid counts (lanes 0..7 hold them), total via wave sum
    int cv0 = 0;
    if (lane < NSUB) cv0 = min(cnt_pad[((c * NSUB + lane) << 4)], SUBCAP);
    int ntot = cv0;
    #pragma unroll
    for (int off = 32; off; off >>= 1) ntot += __shfl_xor(ntot, off);

    ull k16[16]; float4 b16[16]; float c16[16];
    #pragma unroll
    for (int j = 0; j < 16; j++) {
        int pos = lane + (j << 6);
        int sub = pos >> 7;                        // 0..7
        int lim = __shfl(cv0, sub);
        bool ok = (pos & (SUBCAP - 1)) < lim;      // gaps masked; stale data never read
        k16[j] = ok ? key2[s0 + pos] : ~0ULL;
        b16[j] = ok ? box2[s0 + pos] : make_float4(0.f, 0.f, 0.f, 0.f);
        c16[j] = ok ? conf2[s0 + pos] : 0.0f;
    }
    int alive = ntot, np = 0;
    pick_loop<16>(k16, b16, c16, lane, alive, np, pkey, pconf, 256);
    alive = exact_alive(k16);
    ull k4[4]; float4 b4[4]; float c4[4];
    compact_regs<16, 4>(k16, b16, c16, k4, b4, c4, lane, alive, sk, sb, sc);
    pick_loop<4>(k4, b4, c4, lane, alive, np, pkey, pconf, 64);
    alive = exact_alive(k4);
    ull k1[1]; float4 b1[1]; float c1[1];
    compact_regs<4, 1>(k4, b4, c4, k1, b1, c1, lane, alive, sk, sb, sc);
    pick_loop<1>(k1, b1, c1, lane, alive, np, pkey, pconf, 0);

    int npw = min(np, 300);
    int base = 0;
    if (lane == 0 && npw) base = atomicAdd(pool_count, npw);
    base = __shfl(base, 0);
    for (int j = lane; j < npw; j += 64) {
        int pp = base + j;
        if (pp < POOL) {
            ull gm = pkey[j];
            // repack: bit63=0 | 31 score bits | 18 orig_idx | 14 pool_idx
            pool_key[pp] = ((ull)((unsigned)(gm >> 32) & 0x7FFFFFFFu) << 32)
                         | ((gm & 0xFFFFFFFFull) << 14) | (ull)pp;
            pool_conf[pp] = pconf[j];
            pool_cls[pp] = c;
        }
    }
}

// ---------------- single-wave in-register bitonic sort of 512 (8/lane, i = r*64+lane)
__device__ __forceinline__ void bsort512(ull (&x)[8], int lane) {
    #pragma unroll
    for (int k = 2; k <= 512; k <<= 1) {
        #pragma unroll
        for (int j = k >> 1; j >= 64; j >>= 1) {
            const int jr = j >> 6;
            #pragma unroll
            for (int r2 = 0; r2 < 8; r2++) {
                if ((r2 & jr) == 0) {
                    const bool asc = (((r2 << 6) & k) == 0);
                    ull a = x[r2], b = x[r2 | jr];
                    if ((a > b) == asc) { x[r2] = b; x[r2 | jr] = a; }
                }
            }
        }
        #pragma unroll
        for (int j = ((k >> 1) > 32 ? 32 : (k >> 1)); j >= 1; j >>= 1) {
            #pragma unroll
            for (int r2 = 0; r2 < 8; r2++) {
                int i = (r2 << 6) + lane;
                bool asc = ((i & k) == 0);
                ull o = __shfl_xor(x[r2], j);
                bool lower = ((lane & j) == 0);
                ull mn = x[r2] < o ? x[r2] : o;
                ull mx2 = x[r2] < o ? o : x[r2];
                x[r2] = (asc == lower) ? mn : mx2;
            }
        }
    }
}

// ---------------- stage4: prefix-skipped radix-select + single-wave 2-pass sort
__global__ __launch_bounds__(256) void k_final(const ull* __restrict__ pool_key,
                                               const float* __restrict__ pool_conf,
                                               const int* __restrict__ pool_cls,
                                               const int* __restrict__ pool_count,
                                               float* __restrict__ out) {
    __shared__ int s_red[4];
    __shared__ int s_stat[2];
    __shared__ ull s_mm[8];
    __shared__ ull s_buf[512];
    __shared__ unsigned s_cb[512];
    __shared__ unsigned s_cl[512];
    const int t = threadIdx.x, wave = t >> 6, lane = t & 63;
    const int K = min(*pool_count, POOL);
    ull key[32];
    #pragma unroll
    for (int j = 0; j < 32; j++) {
        int pos = t + (j << 8);
        key[j] = (pos < K) ? pool_key[pos] : ~0ULL;
    }

    const bool selAll = (K <= 511);
    int bsh = 63; ull p = 0;
    if (!selAll) {
        ull mn = ~0ULL, mx = 0;
        #pragma unroll
        for (int j = 0; j < 32; j++) {
            ull kk = key[j];
            if (kk != ~0ULL) { if (kk < mn) mn = kk; if (kk > mx) mx = kk; }
        }
        #pragma unroll
        for (int off = 32; off; off >>= 1) {
            ull on = __shfl_xor(mn, off), ox = __shfl_xor(mx, off);
            if (on < mn) mn = on;
            if (ox > mx) mx = ox;
        }
        if (lane == 0) { s_mm[wave * 2] = mn; s_mm[wave * 2 + 1] = mx; }
        __syncthreads();
        mn = min(min(s_mm[0], s_mm[2]), min(s_mm[4], s_mm[6]));
        mx = max(max(s_mm[1], s_mm[3]), max(s_mm[5], s_mm[7]));
        ull diff = mn ^ mx;
        int hb = 63 - __builtin_clzll(diff);
        int r = 300, cand = K, b = hb;
        p = mn >> (hb + 1);
        while (b >= 13 && cand > 212) {
            int c0 = 0;
            #pragma unroll
            for (int j = 0; j < 32; j++) {
                ull kk = key[j];
                if ((kk >> (b + 1)) == p && (((kk >> b) & 1ull) == 0)) c0++;
            }
            #pragma unroll
            for (int off = 32; off; off >>= 1) c0 += __shfl_xor(c0, off);
            if (lane == 0) s_red[wave] = c0;
            __syncthreads();
            if (t == 0) s_stat[0] = s_red[0] + s_red[1] + s_red[2] + s_red[3];
            __syncthreads();
            int cnt0 = s_stat[0];
            if (r <= cnt0) { cand = cnt0; p = p << 1; }
            else { r -= cnt0; cand -= cnt0; p = (p << 1) | 1ull; }
            b--;
        }
        bsh = b + 1;
    }

    if (t == 0) s_stat[1] = 0;
    __syncthreads();
    int ci = 0;
    #pragma unroll
    for (int j = 0; j < 32; j++) {
        ull kk = key[j];
        bool sel = selAll ? ((kk >> 63) == 0) : ((kk >> bsh) <= p);
        if (sel) ci++;
    }
    int inc = ci;
    for (int off = 1; off < 64; off <<= 1) {
        int o = __shfl_up(inc, off);
        if (lane >= off) inc += o;
    }
    int wtot = __shfl(inc, 63);
    int wbase2 = 0;
    if (lane == 0 && wtot) wbase2 = atomicAdd(&s_stat[1], wtot);
    wbase2 = __shfl(wbase2, 0);
    int wp = wbase2 + inc - ci;
    #pragma unroll
    for (int j = 0; j < 32; j++) {
        ull kk = key[j];
        bool sel = selAll ? ((kk >> 63) == 0) : ((kk >> bsh) <= p);
        if (sel) s_buf[wp++] = kk;
    }
    __syncthreads();
    const int S = s_stat[1];
    for (int i = t; i < 512; i += 256) if (i >= S) s_buf[i] = ~0ULL;
    __syncthreads();
    if (wave != 0) return;

    #pragma clang loop unroll(disable)
    for (int pass = 0; pass < 2; pass++) {
        ull x[8];
        #pragma unroll
        for (int r2 = 0; r2 < 8; r2++) x[r2] = s_buf[(r2 << 6) + lane];
        bsort512(x, lane);
        if (pass == 0) {
            #pragma unroll
            for (int r2 = 0; r2 < 8; r2++) {
                int i = (r2 << 6) + lane;
                ull kk = x[r2];
                ull k2 = ~0ULL;
                if (i < 300 && kk != ~0ULL) {
                    int pidx = (int)(kk & 0x3FFFull);
                    unsigned cb = __float_as_uint(pool_conf[pidx]);
                    unsigned cl = (unsigned)pool_cls[pidx];
                    s_cb[i] = cb; s_cl[i] = cl;
                    k2 = ((ull)(~cb) << 32) | (unsigned)(~i);   // conf desc, rank desc
                }
                s_buf[i] = k2;
            }
        } else {
            #pragma unroll
            for (int r2 = 0; r2 < 8; r2++) {
                int i = (r2 << 6) + lane;
                if (i < 300) {
                    ull kk = x[r2];
                    float idv = 0.0f, pv = 0.0f;
                    if (kk != ~0ULL) {
                        int slot = (int)(~(unsigned)(kk & 0xFFFFFFFFull));
                        pv = __uint_as_float(s_cb[slot]);
                        idv = (float)(int)s_cl[slot];
                    }
                    out[i] = idv;        // ids (1,300)
                    out[300 + i] = pv;   // probs (300,)
                }
            }
        }
    }
}

extern "C" void kernel_launch(void* const* d_in, const int* in_sizes, int n_in,
                              void* d_out, int out_size, void* d_ws, size_t ws_size,
                              hipStream_t stream) {
    const float* det = (const float*)d_in[0];
    float* out = (float*)d_out;
    char* ws = (char*)d_ws;

    int* cnt_pad = (int*)(ws + 0);                // 80*8*16*4 = 40960 (1 counter / 64B line)
    int* pool_count = (int*)(ws + 40960);         // 4
    ull* key2 = (ull*)(ws + 41024);               // 80*1024*8 = 655360
    float* conf2 = (float*)(ws + 696384);         // 80*1024*4 = 327680
    float4* box2 = (float4*)(ws + 1024064);       // 80*1024*16 = 1310720 (16B aligned)
    ull* pool_key = (ull*)(ws + 2334784);         // POOL*8 = 65536
    float* pool_conf = (float*)(ws + 2400320);    // POOL*4 = 32768
    int* pool_cls = (int*)(ws + 2433088);         // POOL*4 = 32768

    k_init<<<1, 1024, 0, stream>>>(cnt_pad, pool_count);
    k_stage1<<<NBOX / 256, 256, 0, stream>>>(det, cnt_pad, key2, conf2, box2);
    k_nms<<<NCLS, 64, 0, stream>>>(cnt_pad, key2, conf2, box2,
                                   pool_key, pool_conf, pool_cls, pool_count);
    k_final<<<1, 256, 0, stream>>>(pool_key, pool_conf, pool_cls, pool_count, out);
}